// Round 4
// baseline (316.376 us; speedup 1.0000x reference)
//
#include <hip/hip_runtime.h>
#include <hip/hip_bf16.h>

typedef unsigned short u16;
typedef unsigned int u32;

typedef __bf16 bf16x8 __attribute__((ext_vector_type(8)));
typedef float f32x16 __attribute__((ext_vector_type(16)));

#define AS1 __attribute__((address_space(1)))
#define AS3 __attribute__((address_space(3)))

#define DIN 4096
#define DOUT 4096

__device__ __forceinline__ u16 f2bf(float f) {
    u32 u = __float_as_uint(f);
    u += 0x7fffu + ((u >> 16) & 1u);
    return (u16)(u >> 16);
}

__global__ void cvt_x_kernel(const float4* __restrict__ x, uint4* __restrict__ y, int n8) {
    int stride = gridDim.x * blockDim.x;
    for (int i = blockIdx.x * blockDim.x + threadIdx.x; i < n8; i += stride) {
        float4 f0 = x[2 * i + 0];
        float4 f1 = x[2 * i + 1];
        union { u16 s[8]; uint4 v; } o;
        o.s[0] = f2bf(f0.x); o.s[1] = f2bf(f0.y); o.s[2] = f2bf(f0.z); o.s[3] = f2bf(f0.w);
        o.s[4] = f2bf(f1.x); o.s[5] = f2bf(f1.y); o.s[6] = f2bf(f1.z); o.s[7] = f2bf(f1.w);
        y[i] = o.v;
    }
}

__global__ void cvt_w_kernel(const int4* __restrict__ q, uint4* __restrict__ y, int n8) {
    int stride = gridDim.x * blockDim.x;
    for (int i = blockIdx.x * blockDim.x + threadIdx.x; i < n8; i += stride) {
        int4 q0 = q[2 * i + 0];
        int4 q1 = q[2 * i + 1];
        union { u16 s[8]; uint4 v; } o;
        o.s[0] = f2bf((float)q0.x); o.s[1] = f2bf((float)q0.y);
        o.s[2] = f2bf((float)q0.z); o.s[3] = f2bf((float)q0.w);
        o.s[4] = f2bf((float)q1.x); o.s[5] = f2bf((float)q1.y);
        o.s[6] = f2bf((float)q1.z); o.s[7] = f2bf((float)q1.w);
        y[i] = o.v;
    }
}

// ===== 256x256 4-phase GEMM, 32x32x16 MFMA, swapped-operand epilogue =====
// C[m][n] = scale[n] * sum_k A[m][k]*W[n][k] + bias[n]
// BM=BN=256, BK=64, 512 thr (2Mx4N waves, wave tile 128x64 as 4m x 2n frags of 32x32).
// Phase = {ds-read frags; stage 4 loads; barrier; lgkm0; prio1; 16 MFMA; prio0; [vmcnt(4)]; barrier}

template<int FMB, bool LOADB, bool GATE, typename FStage>
__device__ __forceinline__ void phase32(
    const char* aT, const char* bT,
    const int (&rA)[4], const int (&rB)[2], const int (&sk)[4],
    bf16x8 (&bfr)[2][4], f32x16 (&acc)[4][2], FStage&& st)
{
    bf16x8 afr[2][4];
    if (LOADB) {
#pragma unroll
        for (int fn = 0; fn < 2; ++fn)
#pragma unroll
            for (int kk = 0; kk < 4; ++kk)
                bfr[fn][kk] = *(const bf16x8*)(bT + rB[fn] + sk[kk]);
    }
#pragma unroll
    for (int f = 0; f < 2; ++f)
#pragma unroll
        for (int kk = 0; kk < 4; ++kk)
            afr[f][kk] = *(const bf16x8*)(aT + rA[FMB + f] + sk[kk]);
    st();
    __builtin_amdgcn_s_barrier();
    asm volatile("s_waitcnt lgkmcnt(0)" ::: "memory");
    __builtin_amdgcn_s_setprio(1);
#pragma unroll
    for (int kk = 0; kk < 4; ++kk)
#pragma unroll
        for (int f = 0; f < 2; ++f)
#pragma unroll
            for (int fn = 0; fn < 2; ++fn)
                acc[FMB + f][fn] = __builtin_amdgcn_mfma_f32_32x32x16_bf16(
                    bfr[fn][kk], afr[f][kk], acc[FMB + f][fn], 0, 0, 0);
    __builtin_amdgcn_s_setprio(0);
    if (GATE) asm volatile("s_waitcnt vmcnt(4)" ::: "memory");
    __builtin_amdgcn_s_barrier();
}

__global__ __launch_bounds__(512, 2) void gemm256(
    const u16* __restrict__ A,      // [M][4096] bf16
    const u16* __restrict__ W,      // [4096][4096] bf16
    const float* __restrict__ scale,
    const float* __restrict__ bias,
    float* __restrict__ C,
    int M)
{
    __shared__ alignas(1024) char lds[131072];  // buf0: A@0 B@32768 ; buf1: A@65536 B@98304

    const int nwg = gridDim.x;
    int bid = blockIdx.x;
    if ((nwg & 7) == 0) { int cpx = nwg >> 3; bid = (bid & 7) * cpx + (bid >> 3); }
    const int ntn = DOUT / 256;
    const int tm = bid / ntn, tn = bid % ntn;

    const int t = threadIdx.x;
    const int l = t & 63;
    const int w = t >> 6;
    const int wm = w >> 2, wn = w & 3;       // 2 x 4 wave grid; wave tile 128x64

    // ---- staging: linear LDS dest; pre-swizzled global source (slot p holds logical p^(row&7))
    const int sRow = t >> 3;                             // 0..63 within 64-row chunk
    const int sCol = (((t & 7) ^ ((t >> 3) & 7)) * 8);   // logical element col
    const u16* aSrc = A + (size_t)(tm * 256 + sRow) * DIN + sCol;
    const u16* bSrc = W + (size_t)(tn * 256 + sRow) * DIN + sCol;
    const int wByte = w * 1024;

    const u16* aC[4]; const u16* bC[4];
#pragma unroll
    for (int c = 0; c < 4; ++c) {
        aC[c] = aSrc + (size_t)c * 64 * DIN;
        bC[c] = bSrc + (size_t)c * 64 * DIN;
    }
    char* dA0 = lds + wByte;
    char* dB0 = lds + 32768 + wByte;
    char* dA1 = lds + 65536 + wByte;
    char* dB1 = lds + 98304 + wByte;

    // ---- reader bases. A-frag (32x32x16): row = base + (l&31), k = kk*16 + (l>>5)*8.
    // slot(16B): logical = kk*2 + (l>>5); physical = logical ^ (row&7) = logical ^ (l&7).
    int rA[4], rB[2], sk[4];
#pragma unroll
    for (int f = 0; f < 4; ++f) rA[f] = (wm * 128 + f * 32 + (l & 31)) * 128;
#pragma unroll
    for (int f = 0; f < 2; ++f) rB[f] = (wn * 64 + f * 32 + (l & 31)) * 128;
#pragma unroll
    for (int kk = 0; kk < 4; ++kk) sk[kk] = ((((kk << 1) | (l >> 5)) ^ (l & 7)) << 4);

    const char* aX = lds;
    const char* bX = lds + 32768;
    const char* aY = lds + 65536;
    const char* bY = lds + 98304;

    f32x16 acc[4][2];
#pragma unroll
    for (int i = 0; i < 4; ++i)
#pragma unroll
        for (int j = 0; j < 2; ++j) acc[i][j] = (f32x16)(0.f);

    auto stA = [&](char* dst, int kt) {
#pragma unroll
        for (int c = 0; c < 4; ++c)
            __builtin_amdgcn_global_load_lds((const AS1 void*)(aC[c] + (size_t)kt * 64),
                (AS3 void*)(dst + c * 8192), 16, 0, 0);
    };
    auto stB = [&](char* dst, int kt) {
#pragma unroll
        for (int c = 0; c < 4; ++c)
            __builtin_amdgcn_global_load_lds((const AS1 void*)(bC[c] + (size_t)kt * 64),
                (AS3 void*)(dst + c * 8192), 16, 0, 0);
    };

    const int NT = DIN / 64;   // 64 K-tiles

    // ---- prologue: B(0),A(0) -> buf0; B(1) -> buf1; counted gate (drains 8, keeps B(1))
    stB(dB0, 0);
    stA(dA0, 0);
    stB(dB1, 1);
    asm volatile("s_waitcnt vmcnt(4)" ::: "memory");
    __builtin_amdgcn_s_barrier();

    bf16x8 bfr[2][4];

    // ---- main loop: 2 K-tiles / iter, 4 phases. Consumption: P1 frees X.A{chunks 0,2}+X.B,
    // P2 frees X.A{1,3}; P3/P4 same on Y. Gates vmcnt(4) at P2,P4 cover next consumers.
#pragma unroll 1
    for (int i = 0; i < NT / 2; ++i) {
        const int y = 2 * i + 1;
        const int e = (2 * i + 2) & (NT - 1);
        const int o = (2 * i + 3) & (NT - 1);
        phase32<0, true , false>(aX, bX, rA, rB, sk, bfr, acc, [&] { stA(dA1, y); });
        phase32<2, false, true >(aX, bX, rA, rB, sk, bfr, acc, [&] { stB(dB0, e); });
        phase32<0, true , false>(aY, bY, rA, rB, sk, bfr, acc, [&] { stA(dA0, e); });
        phase32<2, false, true >(aY, bY, rA, rB, sk, bfr, acc, [&] { stB(dB1, o); });
    }

    // ---- epilogue: swapped-operand D layout: m = mB + (l&31) (fixed per lane),
    // n = nB + fn*32 + q*8 + 4*(l>>5) + (0..3)  -> float4 stores, float4 scale/bias
    const int mB = tm * 256 + wm * 128 + (l & 31);
    const int nB = tn * 256 + wn * 64 + 4 * (l >> 5);
#pragma unroll
    for (int fn = 0; fn < 2; ++fn) {
#pragma unroll
        for (int q = 0; q < 4; ++q) {
            const int n0 = nB + fn * 32 + q * 8;
            const float4 s4 = *(const float4*)(scale + n0);
            const float4 b4 = *(const float4*)(bias + n0);
#pragma unroll
            for (int fm = 0; fm < 4; ++fm) {
                const int m = mB + fm * 32;
                float4 v;
                v.x = acc[fm][fn][4 * q + 0] * s4.x + b4.x;
                v.y = acc[fm][fn][4 * q + 1] * s4.y + b4.y;
                v.z = acc[fm][fn][4 * q + 2] * s4.z + b4.z;
                v.w = acc[fm][fn][4 * q + 3] * s4.w + b4.w;
                *(float4*)(C + (size_t)m * DOUT + n0) = v;
            }
        }
    }
}

extern "C" void kernel_launch(void* const* d_in, const int* in_sizes, int n_in,
                              void* d_out, int out_size, void* d_ws, size_t ws_size,
                              hipStream_t stream) {
    const float* x     = (const float*)d_in[0];
    const int*   qw    = (const int*)d_in[1];
    const float* scale = (const float*)d_in[2];
    const float* bias  = (const float*)d_in[3];
    float*       out   = (float*)d_out;

    const int N = in_sizes[2];            // DOUT = 4096
    const int K = in_sizes[1] / N;        // DIN  = 4096
    const int M = in_sizes[0] / K;        // B*S  = 8192

    u16* xb = (u16*)d_ws;
    u16* wb = xb + (size_t)M * K;

    cvt_x_kernel<<<2048, 256, 0, stream>>>((const float4*)x, (uint4*)xb, (M * K) / 8);
    cvt_w_kernel<<<2048, 256, 0, stream>>>((const int4*)qw, (uint4*)wb, (N * K) / 8);

    const int grid = (M / 256) * (N / 256); // 512
    gemm256<<<grid, 512, 0, stream>>>(xb, wb, scale, bias, out, M);
}

// Round 5
// 275.544 us; speedup vs baseline: 1.1482x; 1.1482x over previous
//
#include <hip/hip_runtime.h>
#include <hip/hip_bf16.h>

typedef unsigned short u16;
typedef unsigned int u32;

typedef __bf16 bf16x8 __attribute__((ext_vector_type(8)));
typedef float f32x4 __attribute__((ext_vector_type(4)));

#define AS1 __attribute__((address_space(1)))
#define AS3 __attribute__((address_space(3)))

__device__ __forceinline__ u16 f2bf(float f) {
    u32 u = __float_as_uint(f);
    u += 0x7fffu + ((u >> 16) & 1u);
    return (u16)(u >> 16);
}

__global__ void cvt_x_kernel(const float4* __restrict__ x, uint4* __restrict__ y, int n8) {
    int stride = gridDim.x * blockDim.x;
    for (int i = blockIdx.x * blockDim.x + threadIdx.x; i < n8; i += stride) {
        float4 f0 = x[2 * i + 0];
        float4 f1 = x[2 * i + 1];
        union { u16 s[8]; uint4 v; } o;
        o.s[0] = f2bf(f0.x); o.s[1] = f2bf(f0.y); o.s[2] = f2bf(f0.z); o.s[3] = f2bf(f0.w);
        o.s[4] = f2bf(f1.x); o.s[5] = f2bf(f1.y); o.s[6] = f2bf(f1.z); o.s[7] = f2bf(f1.w);
        y[i] = o.v;
    }
}

__global__ void cvt_w_kernel(const int4* __restrict__ q, uint4* __restrict__ y, int n8) {
    int stride = gridDim.x * blockDim.x;
    for (int i = blockIdx.x * blockDim.x + threadIdx.x; i < n8; i += stride) {
        int4 q0 = q[2 * i + 0];
        int4 q1 = q[2 * i + 1];
        union { u16 s[8]; uint4 v; } o;
        o.s[0] = f2bf((float)q0.x); o.s[1] = f2bf((float)q0.y);
        o.s[2] = f2bf((float)q0.z); o.s[3] = f2bf((float)q0.w);
        o.s[4] = f2bf((float)q1.x); o.s[5] = f2bf((float)q1.y);
        o.s[6] = f2bf((float)q1.z); o.s[7] = f2bf((float)q1.w);
        y[i] = o.v;
    }
}

// ===== 256x256 GEMM, 16x16x32 MFMA, 3-bit slot swizzle, SINGLE-barrier phases =====
// C[m][n] = scale[n] * sum_k A[m][k]*W[n][k] + bias[n]
// BM=BN=256, BK=64, 512 thr (2Mx4N waves). Phase = one barrier region:
// {stage-issue; ds_reads; prio1; 16 MFMA (compiler interleaves via fine lgkm); prio0; [vmcnt(4)]; barrier}
// Hazard proof: every ds_read is consumed by an in-phase MFMA (=> complete before the
// wave's phase barrier); staging of phase P issues after collective barrier(P-1->P);
// new-data visibility guarded by vmcnt(4) gates at P4/P8 (unchanged from verified R3).

#define BM 256
#define BN 256
#define BK 64

template<int KS, int MLO, bool GATE, typename F>
__device__ __forceinline__ void phase(const char* aB, const char* bB,
    bf16x8 (&bfr)[2][4], f32x4 (&acc)[8][4], F&& stage)
{
    stage();
    bf16x8 afr[4];
    if (MLO == 0) {
#pragma unroll
        for (int fn = 0; fn < 4; ++fn)
            bfr[KS][fn] = *(const bf16x8*)(bB + fn * 2048);
    }
#pragma unroll
    for (int fm = 0; fm < 4; ++fm)
        afr[fm] = *(const bf16x8*)(aB + (MLO + fm) * 2048);
    __builtin_amdgcn_s_setprio(1);
#pragma unroll
    for (int fm = 0; fm < 4; ++fm)
#pragma unroll
        for (int fn = 0; fn < 4; ++fn)
            acc[MLO + fm][fn] = __builtin_amdgcn_mfma_f32_16x16x32_bf16(
                afr[fm], bfr[KS][fn], acc[MLO + fm][fn], 0, 0, 0);
    __builtin_amdgcn_s_setprio(0);
    if (GATE) asm volatile("s_waitcnt vmcnt(4)" ::: "memory");
    __builtin_amdgcn_s_barrier();
}

__global__ __launch_bounds__(512, 2) void gemm256(
    const u16* __restrict__ A,      // [M][K] bf16
    const u16* __restrict__ W,      // [N][K] bf16
    const float* __restrict__ scale,
    const float* __restrict__ bias,
    float* __restrict__ C,
    int M, int N, int K)
{
    __shared__ alignas(1024) char lds[131072];  // buf0: A@0 B@32768 ; buf1: A@65536 B@98304

    const int nwg = gridDim.x;
    int bid = blockIdx.x;
    if ((nwg & 7) == 0) { int cpx = nwg >> 3; bid = (bid & 7) * cpx + (bid >> 3); }
    const int ntn = N / BN;
    const int tm = bid / ntn, tn = bid % ntn;

    const int t = threadIdx.x;
    const int l = t & 63;
    const int w = t >> 6;
    const int wm = w >> 2, wn = w & 3;       // 2 x 4 wave grid; wave tile 128x64
    const size_t Kz = (size_t)K;

    // ---- staging: linear LDS dest (wave base + lane*16); PRE-SWIZZLED global source.
    // physical slot p = t&7 at row t>>3 holds logical slot p ^ (row&7).
    const int sRow = t >> 3;                             // 0..63 within 64-row chunk
    const int sCol = (((t & 7) ^ ((t >> 3) & 7)) * 8);   // logical element col
    const u16* aSrc = A + (size_t)(tm * BM + sRow) * Kz + sCol;
    const u16* bSrc = W + (size_t)(tn * BN + sRow) * Kz + sCol;
    const int wByte = w * 1024;

    char* dA0 = lds + wByte;
    char* dB0 = lds + 32768 + wByte;
    char* dA1 = lds + 65536 + wByte;
    char* dB1 = lds + 98304 + wByte;

    // ---- reader bases: logical slot = (l>>4) | (KS<<2); physical = logical ^ (l&7).
    // row&7 == l&7 for all fragment rows (frag offsets are multiples of 16).
    const int rowA = (wm * 128 + (l & 15)) * 128;
    const int rowB = (wn * 64  + (l & 15)) * 128;
    const int sl0 = (((l >> 4) | 0) ^ (l & 7)) * 16;   // KS=0 slot byte
    const int sl1 = (((l >> 4) | 4) ^ (l & 7)) * 16;   // KS=1 slot byte

    const char* aX0 = lds +         rowA + sl0;
    const char* aX1 = lds +         rowA + sl1;
    const char* bX0 = lds + 32768 + rowB + sl0;
    const char* bX1 = lds + 32768 + rowB + sl1;
    const char* aY0 = lds + 65536 + rowA + sl0;
    const char* aY1 = lds + 65536 + rowA + sl1;
    const char* bY0 = lds + 98304 + rowB + sl0;
    const char* bY1 = lds + 98304 + rowB + sl1;

    f32x4 acc[8][4];
#pragma unroll
    for (int i = 0; i < 8; ++i)
#pragma unroll
        for (int j = 0; j < 4; ++j) acc[i][j] = (f32x4){0.f, 0.f, 0.f, 0.f};

    const int NT = K / BK;   // 64 K-tiles

    auto stagePair = [&](const u16* src, char* dst, int kt, int c0, int c1) {
        const u16* s0 = src + (size_t)c0 * 64 * Kz + (size_t)kt * 64;
        const u16* s1 = src + (size_t)c1 * 64 * Kz + (size_t)kt * 64;
        __builtin_amdgcn_global_load_lds((const AS1 void*)s0, (AS3 void*)(dst + c0 * 8192), 16, 0, 0);
        __builtin_amdgcn_global_load_lds((const AS1 void*)s1, (AS3 void*)(dst + c1 * 8192), 16, 0, 0);
    };

    // ---- prologue: tile0 full -> buf0; tile1 B -> buf1; counted gate
    stagePair(aSrc, dA0, 0, 0, 2);
    stagePair(bSrc, dB0, 0, 0, 1);
    stagePair(bSrc, dB0, 0, 2, 3);
    stagePair(aSrc, dA0, 0, 1, 3);
    stagePair(bSrc, dB1, 1, 0, 1);
    stagePair(bSrc, dB1, 1, 2, 3);
    asm volatile("s_waitcnt vmcnt(4)" ::: "memory");
    __builtin_amdgcn_s_barrier();

    bf16x8 bfr[2][4];

    // ---- main loop: 2 K-tiles per iteration, 8 single-barrier phases.
    // Stage schedule (vmcnt(4)@P4,P8 provably covers every consumed chunk):
    //  P1:(2i+1).A02->buf1  P2:(2i+1).A13->buf1  P3:e.A02->buf0  P4:e.B01->buf0 +gate
    //  P5:e.B23->buf0       P6:e.A13->buf0       P7:o.B01->buf1  P8:o.B23->buf1 +gate
#pragma unroll 1
    for (int i = 0; i < NT / 2; ++i) {
        const int yt = 2 * i + 1;
        const int e  = (2 * i + 2) & (NT - 1);   // wraps harmlessly on last iter
        const int o  = (2 * i + 3) & (NT - 1);
        phase<0, 0, false>(aX0, bX0, bfr, acc, [&] { stagePair(aSrc, dA1, yt, 0, 2); });
        phase<1, 0, false>(aX1, bX1, bfr, acc, [&] { stagePair(aSrc, dA1, yt, 1, 3); });
        phase<0, 4, false>(aX0, bX0, bfr, acc, [&] { stagePair(aSrc, dA0, e, 0, 2); });
        phase<1, 4, true >(aX1, bX1, bfr, acc, [&] { stagePair(bSrc, dB0, e, 0, 1); });
        phase<0, 0, false>(aY0, bY0, bfr, acc, [&] { stagePair(bSrc, dB0, e, 2, 3); });
        phase<1, 0, false>(aY1, bY1, bfr, acc, [&] { stagePair(aSrc, dA0, e, 1, 3); });
        phase<0, 4, false>(aY0, bY0, bfr, acc, [&] { stagePair(bSrc, dB1, o, 0, 1); });
        phase<1, 4, true >(aY1, bY1, bfr, acc, [&] { stagePair(bSrc, dB1, o, 2, 3); });
    }

    // ---- epilogue: C/D frag (16x16x32): col = lane&15, row = (lane>>4)*4 + reg
    const int colb = tn * BN + wn * 64 + (l & 15);
    const int rowb = tm * BM + wm * 128 + (l >> 4) * 4;
#pragma unroll
    for (int fn = 0; fn < 4; ++fn) {
        const int col = colb + fn * 16;
        const float s = scale[col];
        const float b = bias[col];
#pragma unroll
        for (int fm = 0; fm < 8; ++fm) {
            const int row = rowb + fm * 16;
#pragma unroll
            for (int r = 0; r < 4; ++r)
                C[(size_t)(row + r) * N + col] = acc[fm][fn][r] * s + b;
        }
    }
}

extern "C" void kernel_launch(void* const* d_in, const int* in_sizes, int n_in,
                              void* d_out, int out_size, void* d_ws, size_t ws_size,
                              hipStream_t stream) {
    const float* x     = (const float*)d_in[0];
    const int*   qw    = (const int*)d_in[1];
    const float* scale = (const float*)d_in[2];
    const float* bias  = (const float*)d_in[3];
    float*       out   = (float*)d_out;

    const int N = in_sizes[2];            // DOUT = 4096
    const int K = in_sizes[1] / N;        // DIN  = 4096
    const int M = in_sizes[0] / K;        // B*S  = 8192

    u16* xb = (u16*)d_ws;
    u16* wb = xb + (size_t)M * K;

    cvt_x_kernel<<<2048, 256, 0, stream>>>((const float4*)x, (uint4*)xb, (M * K) / 8);
    cvt_w_kernel<<<2048, 256, 0, stream>>>((const int4*)qw, (uint4*)wb, (N * K) / 8);

    const int grid = (M / BM) * (N / BN); // 512
    gemm256<<<grid, 512, 0, stream>>>(xb, wb, scale, bias, out, M, N, K);
}

// Round 6
// 269.999 us; speedup vs baseline: 1.1718x; 1.0205x over previous
//
#include <hip/hip_runtime.h>
#include <hip/hip_bf16.h>

typedef unsigned short u16;
typedef unsigned int u32;

typedef __bf16 bf16x8 __attribute__((ext_vector_type(8)));
typedef float f32x4 __attribute__((ext_vector_type(4)));

#define AS1 __attribute__((address_space(1)))
#define AS3 __attribute__((address_space(3)))

__device__ __forceinline__ u16 f2bf(float f) {
    u32 u = __float_as_uint(f);
    u += 0x7fffu + ((u >> 16) & 1u);
    return (u16)(u >> 16);
}

__global__ void cvt_x_kernel(const float4* __restrict__ x, uint4* __restrict__ y, int n8) {
    int stride = gridDim.x * blockDim.x;
    for (int i = blockIdx.x * blockDim.x + threadIdx.x; i < n8; i += stride) {
        float4 f0 = x[2 * i + 0];
        float4 f1 = x[2 * i + 1];
        union { u16 s[8]; uint4 v; } o;
        o.s[0] = f2bf(f0.x); o.s[1] = f2bf(f0.y); o.s[2] = f2bf(f0.z); o.s[3] = f2bf(f0.w);
        o.s[4] = f2bf(f1.x); o.s[5] = f2bf(f1.y); o.s[6] = f2bf(f1.z); o.s[7] = f2bf(f1.w);
        y[i] = o.v;
    }
}

__global__ void cvt_w_kernel(const int4* __restrict__ q, uint4* __restrict__ y, int n8) {
    int stride = gridDim.x * blockDim.x;
    for (int i = blockIdx.x * blockDim.x + threadIdx.x; i < n8; i += stride) {
        int4 q0 = q[2 * i + 0];
        int4 q1 = q[2 * i + 1];
        union { u16 s[8]; uint4 v; } o;
        o.s[0] = f2bf((float)q0.x); o.s[1] = f2bf((float)q0.y);
        o.s[2] = f2bf((float)q0.z); o.s[3] = f2bf((float)q0.w);
        o.s[4] = f2bf((float)q1.x); o.s[5] = f2bf((float)q1.y);
        o.s[6] = f2bf((float)q1.z); o.s[7] = f2bf((float)q1.w);
        y[i] = o.v;
    }
}

// ===== 256x256 GEMM, 4 phases/iter of 32 MFMA (K=64 chained), swapped-operand D =====
// C[m][n] = scale[n] * sum_k A[m][k]*W[n][k] + bias[n]
// BM=BN=256, BK=64, 512 thr (2Mx4N waves). Phase = one barrier region:
// {stage 2 pairs; ds_reads (8 or 16 b128); prio1; 32 MFMA; prio0; [vmcnt(4)]; barrier}
// Ledger: every staged chunk is >=1 barrier past its last reader (in-phase MFMA
// consumption forces ds_read completion before the phase's end barrier). Gates
// vmcnt(4) at P2/P4 cover all consumers; youngest drained load is 1 phase old.

#define BM 256
#define BN 256
#define BK 64

template<int MLO, bool LOADB, bool GATE, typename F>
__device__ __forceinline__ void phase4(
    const char* aB0, const char* aB1, const char* bB0, const char* bB1,
    bf16x8 (&bfr)[4][2], f32x4 (&acc)[8][4], F&& stage)
{
    stage();
    bf16x8 afr[4][2];
    if (LOADB) {
#pragma unroll
        for (int fn = 0; fn < 4; ++fn) {
            bfr[fn][0] = *(const bf16x8*)(bB0 + fn * 2048);
            bfr[fn][1] = *(const bf16x8*)(bB1 + fn * 2048);
        }
    }
#pragma unroll
    for (int f = 0; f < 4; ++f) {
        afr[f][0] = *(const bf16x8*)(aB0 + (MLO + f) * 2048);
        afr[f][1] = *(const bf16x8*)(aB1 + (MLO + f) * 2048);
    }
    __builtin_amdgcn_s_setprio(1);
#pragma unroll
    for (int f = 0; f < 4; ++f)
#pragma unroll
        for (int fn = 0; fn < 4; ++fn) {
            // swapped operands: D[row->n][col->m]
            f32x4 tmp = __builtin_amdgcn_mfma_f32_16x16x32_bf16(
                bfr[fn][0], afr[f][0], acc[MLO + f][fn], 0, 0, 0);
            acc[MLO + f][fn] = __builtin_amdgcn_mfma_f32_16x16x32_bf16(
                bfr[fn][1], afr[f][1], tmp, 0, 0, 0);
        }
    __builtin_amdgcn_s_setprio(0);
    if (GATE) asm volatile("s_waitcnt vmcnt(4)" ::: "memory");
    __builtin_amdgcn_s_barrier();
}

__global__ __launch_bounds__(512, 2) void gemm256(
    const u16* __restrict__ A,      // [M][K] bf16
    const u16* __restrict__ W,      // [N][K] bf16
    const float* __restrict__ scale,
    const float* __restrict__ bias,
    float* __restrict__ C,
    int M, int N, int K)
{
    __shared__ alignas(1024) char lds[131072];  // buf0: A@0 B@32768 ; buf1: A@65536 B@98304

    const int nwg = gridDim.x;
    int bid = blockIdx.x;
    if ((nwg & 7) == 0) { int cpx = nwg >> 3; bid = (bid & 7) * cpx + (bid >> 3); }
    const int ntn = N / BN;
    const int tm = bid / ntn, tn = bid % ntn;

    const int t = threadIdx.x;
    const int l = t & 63;
    const int w = t >> 6;
    const int wm = w >> 2, wn = w & 3;       // 2 x 4 wave grid; wave tile 128x64
    const size_t Kz = (size_t)K;

    // ---- staging: linear LDS dest (wave base + lane*16); PRE-SWIZZLED global source.
    // physical slot p = t&7 at row t>>3 holds logical slot p ^ (row&7).
    const int sRow = t >> 3;                             // 0..63 within 64-row chunk
    const int sCol = (((t & 7) ^ ((t >> 3) & 7)) * 8);   // logical element col
    const u16* aSrc = A + (size_t)(tm * BM + sRow) * Kz + sCol;
    const u16* bSrc = W + (size_t)(tn * BN + sRow) * Kz + sCol;
    const int wByte = w * 1024;

    char* dA0 = lds + wByte;
    char* dB0 = lds + 32768 + wByte;
    char* dA1 = lds + 65536 + wByte;
    char* dB1 = lds + 98304 + wByte;

    // ---- reader bases: logical slot = (l>>4) | (KS<<2); physical = logical ^ (l&7).
    const int rowA = (wm * 128 + (l & 15)) * 128;
    const int rowB = (wn * 64  + (l & 15)) * 128;
    const int sl0 = (((l >> 4) | 0) ^ (l & 7)) * 16;   // KS=0 slot byte
    const int sl1 = (((l >> 4) | 4) ^ (l & 7)) * 16;   // KS=1 slot byte

    const char* aX0 = lds +         rowA + sl0;
    const char* aX1 = lds +         rowA + sl1;
    const char* bX0 = lds + 32768 + rowB + sl0;
    const char* bX1 = lds + 32768 + rowB + sl1;
    const char* aY0 = lds + 65536 + rowA + sl0;
    const char* aY1 = lds + 65536 + rowA + sl1;
    const char* bY0 = lds + 98304 + rowB + sl0;
    const char* bY1 = lds + 98304 + rowB + sl1;

    f32x4 acc[8][4];
#pragma unroll
    for (int i = 0; i < 8; ++i)
#pragma unroll
        for (int j = 0; j < 4; ++j) acc[i][j] = (f32x4){0.f, 0.f, 0.f, 0.f};

    const int NT = K / BK;   // 64 K-tiles

    auto stagePair = [&](const u16* src, char* dst, int kt, int c0, int c1) {
        const u16* s0 = src + (size_t)c0 * 64 * Kz + (size_t)kt * 64;
        const u16* s1 = src + (size_t)c1 * 64 * Kz + (size_t)kt * 64;
        __builtin_amdgcn_global_load_lds((const AS1 void*)s0, (AS3 void*)(dst + c0 * 8192), 16, 0, 0);
        __builtin_amdgcn_global_load_lds((const AS1 void*)s1, (AS3 void*)(dst + c1 * 8192), 16, 0, 0);
    };

    // ---- prologue: tile0 full -> buf0; tile1 A{0,2}+B{0,1} -> buf1; counted gate
    stagePair(aSrc, dA0, 0, 0, 2);
    stagePair(bSrc, dB0, 0, 0, 1);
    stagePair(bSrc, dB0, 0, 2, 3);
    stagePair(aSrc, dA0, 0, 1, 3);
    stagePair(aSrc, dA1, 1, 0, 2);
    stagePair(bSrc, dB1, 1, 0, 1);
    asm volatile("s_waitcnt vmcnt(4)" ::: "memory");
    __builtin_amdgcn_s_barrier();

    bf16x8 bfr[4][2];

    // ---- main loop: 2 K-tiles / iter, 4 phases of 32 MFMA.
    // P1: reads A-X{0,2}+B-X; stage B-Y{2,3},A-Y{1,3}
    // P2: reads A-X{1,3};     stage A-X'{0,2},B-X'{0,1}; GATE vmcnt(4)
    // P3: reads A-Y{0,2}+B-Y; stage B-X'{2,3},A-X'{1,3}
    // P4: reads A-Y{1,3};     stage A-Y'{0,2},B-Y'{0,1}; GATE vmcnt(4)
#pragma unroll 1
    for (int i = 0; i < NT / 2; ++i) {
        const int yt = 2 * i + 1;
        const int e  = (2 * i + 2) & (NT - 1);   // wraps harmlessly on last iter
        const int o  = (2 * i + 3) & (NT - 1);
        phase4<0, true , false>(aX0, aX1, bX0, bX1, bfr, acc, [&] {
            stagePair(bSrc, dB1, yt, 2, 3); stagePair(aSrc, dA1, yt, 1, 3); });
        phase4<4, false, true >(aX0, aX1, bX0, bX1, bfr, acc, [&] {
            stagePair(aSrc, dA0, e, 0, 2); stagePair(bSrc, dB0, e, 0, 1); });
        phase4<0, true , false>(aY0, aY1, bY0, bY1, bfr, acc, [&] {
            stagePair(bSrc, dB0, e, 2, 3); stagePair(aSrc, dA0, e, 1, 3); });
        phase4<4, false, true >(aY0, aY1, bY0, bY1, bfr, acc, [&] {
            stagePair(aSrc, dA1, o, 0, 2); stagePair(bSrc, dB1, o, 0, 1); });
    }

    // ---- epilogue (swapped D): col(l&15) -> m, row((l>>4)*4+r) -> n
    // m = tm*256 + wm*128 + f*16 + (l&15); n = tn*256 + wn*64 + fn*16 + (l>>4)*4 + r
    const int mB = tm * BM + wm * 128 + (l & 15);
    const int nB = tn * BN + wn * 64 + 4 * (l >> 4);
#pragma unroll
    for (int fn = 0; fn < 4; ++fn) {
        const int n0 = nB + fn * 16;
        const float4 s4 = *(const float4*)(scale + n0);
        const float4 b4 = *(const float4*)(bias + n0);
#pragma unroll
        for (int f = 0; f < 8; ++f) {
            const int m = mB + f * 16;
            float4 v;
            v.x = acc[f][fn][0] * s4.x + b4.x;
            v.y = acc[f][fn][1] * s4.y + b4.y;
            v.z = acc[f][fn][2] * s4.z + b4.z;
            v.w = acc[f][fn][3] * s4.w + b4.w;
            *(float4*)(C + (size_t)m * N + n0) = v;
        }
    }
}

extern "C" void kernel_launch(void* const* d_in, const int* in_sizes, int n_in,
                              void* d_out, int out_size, void* d_ws, size_t ws_size,
                              hipStream_t stream) {
    const float* x     = (const float*)d_in[0];
    const int*   qw    = (const int*)d_in[1];
    const float* scale = (const float*)d_in[2];
    const float* bias  = (const float*)d_in[3];
    float*       out   = (float*)d_out;

    const int N = in_sizes[2];            // DOUT = 4096
    const int K = in_sizes[1] / N;        // DIN  = 4096
    const int M = in_sizes[0] / K;        // B*S  = 8192

    u16* xb = (u16*)d_ws;
    u16* wb = xb + (size_t)M * K;

    cvt_x_kernel<<<2048, 256, 0, stream>>>((const float4*)x, (uint4*)xb, (M * K) / 8);
    cvt_w_kernel<<<2048, 256, 0, stream>>>((const int4*)qw, (uint4*)wb, (N * K) / 8);

    const int grid = (M / BM) * (N / BN); // 512
    gemm256<<<grid, 512, 0, stream>>>(xb, wb, scale, bias, out, M, N, K);
}

// Round 7
// 180.148 us; speedup vs baseline: 1.7562x; 1.4988x over previous
//
#include <hip/hip_runtime.h>

typedef unsigned short u16;
typedef unsigned int u32;
typedef unsigned char u8;

typedef int i32x4 __attribute__((ext_vector_type(4)));
typedef float f32x4 __attribute__((ext_vector_type(4)));

#define AS1 __attribute__((address_space(1)))
#define AS3 __attribute__((address_space(3)))

// ---- per-row symmetric i8 quantization of x: one block (256 thr) per row ----
// W is int4 codes in [-8,7]: EXACT in i8 (zero error); only x carries quant error.
__global__ __launch_bounds__(256) void quant_x_kernel(
    const float* __restrict__ x, u8* __restrict__ xq, float* __restrict__ sx, int K)
{
    const int r = blockIdx.x;
    const int t = threadIdx.x;
    const float* xr = x + (size_t)r * K;
    float4 v[4];
    float m = 0.f;
#pragma unroll
    for (int i = 0; i < 4; ++i) {
        v[i] = *(const float4*)(xr + t * 16 + i * 4);
        m = fmaxf(m, fmaxf(fmaxf(fabsf(v[i].x), fabsf(v[i].y)),
                           fmaxf(fabsf(v[i].z), fabsf(v[i].w))));
    }
#pragma unroll
    for (int s = 32; s; s >>= 1) m = fmaxf(m, __shfl_xor(m, s));
    __shared__ float wm[4];
    if ((t & 63) == 0) wm[t >> 6] = m;
    __syncthreads();
    m = fmaxf(fmaxf(wm[0], wm[1]), fmaxf(wm[2], wm[3]));
    const float inv = 127.f / fmaxf(m, 1e-20f);
    if (t == 0) sx[r] = m * (1.f / 127.f);
    u32 o[4];
#pragma unroll
    for (int i = 0; i < 4; ++i) {
        int q0 = (int)rintf(v[i].x * inv), q1 = (int)rintf(v[i].y * inv);
        int q2 = (int)rintf(v[i].z * inv), q3 = (int)rintf(v[i].w * inv);
        o[i] = (u32)(q0 & 255) | ((u32)(q1 & 255) << 8) |
               ((u32)(q2 & 255) << 16) | ((u32)(q3 & 255) << 24);
    }
    *(uint4*)(xq + (size_t)r * K + t * 16) = make_uint4(o[0], o[1], o[2], o[3]);
}

__device__ __forceinline__ u32 pk8(int4 a) {
    return (u32)(a.x & 255) | ((u32)(a.y & 255) << 8) |
           ((u32)(a.z & 255) << 16) | ((u32)(a.w & 255) << 24);
}

// int32 codes [-8,7] -> i8 (exact)
__global__ void quant_w_kernel(const int4* __restrict__ q, uint4* __restrict__ y, int n16) {
    int stride = gridDim.x * blockDim.x;
    for (int i = blockIdx.x * blockDim.x + threadIdx.x; i < n16; i += stride) {
        int4 a = q[4 * i], b = q[4 * i + 1], c = q[4 * i + 2], d = q[4 * i + 3];
        y[i] = make_uint4(pk8(a), pk8(b), pk8(c), pk8(d));
    }
}

// ===== 256x256 i8 GEMM: mfma_i32_16x16x64_i8, BK=128 (bytes/row=128, 8 slots),
// 8 single-barrier phases / 2 K-tiles, 3-bit slot swizzle, swapped-operand D. =====
// out[m][n] = acc[m][n] * sx[m] * scale[n] + bias[n]
// Structure, LDS layout, stage schedule, and gates are byte-identical to the
// verified bf16-R5 kernel (u16 elems -> u8, K-tile 64 -> 128).

#define BM 256
#define BN 256
#define BKB 128   // K-bytes per tile (=128 i8)

template<int KS, int MLO, bool GATE, typename F>
__device__ __forceinline__ void phase(const char* aB, const char* bB,
    i32x4 (&bfr)[2][4], i32x4 (&acc)[8][4], F&& stage)
{
    stage();
    i32x4 afr[4];
    if (MLO == 0) {
#pragma unroll
        for (int fn = 0; fn < 4; ++fn)
            bfr[KS][fn] = *(const i32x4*)(bB + fn * 2048);
    }
#pragma unroll
    for (int fm = 0; fm < 4; ++fm)
        afr[fm] = *(const i32x4*)(aB + (MLO + fm) * 2048);
    __builtin_amdgcn_s_setprio(1);
#pragma unroll
    for (int fm = 0; fm < 4; ++fm)
#pragma unroll
        for (int fn = 0; fn < 4; ++fn)
            acc[MLO + fm][fn] = __builtin_amdgcn_mfma_i32_16x16x64_i8(
                bfr[KS][fn], afr[fm], acc[MLO + fm][fn], 0, 0, 0);  // swapped: D col->m
    __builtin_amdgcn_s_setprio(0);
    if (GATE) asm volatile("s_waitcnt vmcnt(4)" ::: "memory");
    __builtin_amdgcn_s_barrier();
}

__global__ __launch_bounds__(512, 2) void gemm256_i8(
    const u8* __restrict__ A,       // [M][K] i8 (x quantized per-row)
    const u8* __restrict__ W,       // [N][K] i8 (exact int4)
    const float* __restrict__ sx,   // [M] x row scales
    const float* __restrict__ scale,
    const float* __restrict__ bias,
    float* __restrict__ C,
    int M, int N, int K)
{
    __shared__ alignas(1024) char lds[131072];  // buf0: A@0 B@32768 ; buf1: A@65536 B@98304

    const int nwg = gridDim.x;
    int bid = blockIdx.x;
    if ((nwg & 7) == 0) { int cpx = nwg >> 3; bid = (bid & 7) * cpx + (bid >> 3); }
    const int ntn = N / BN;
    const int tm = bid / ntn, tn = bid % ntn;

    const int t = threadIdx.x;
    const int l = t & 63;
    const int w = t >> 6;
    const int wm = w >> 2, wn = w & 3;       // 2 x 4 wave grid; wave tile 128x64
    const size_t Kz = (size_t)K;             // row stride in BYTES (i8)

    // ---- staging: linear LDS dest; pre-swizzled global source.
    // physical 16B-slot p at row (t>>3) holds logical slot p ^ (row&7).
    const int sRow = t >> 3;                              // 0..63 within 64-row chunk
    const int sCol = (((t & 7) ^ ((t >> 3) & 7)) * 16);   // logical byte offset in row
    const u8* aSrc = A + (size_t)(tm * BM + sRow) * Kz + sCol;
    const u8* bSrc = W + (size_t)(tn * BN + sRow) * Kz + sCol;
    const int wByte = w * 1024;

    char* dA0 = lds + wByte;
    char* dB0 = lds + 32768 + wByte;
    char* dA1 = lds + 65536 + wByte;
    char* dB1 = lds + 98304 + wByte;

    // ---- reader bases: logical slot = (l>>4) | (KS<<2); physical = logical ^ (l&7).
    // row&7 == l&7 for all fragment rows (frag offsets are multiples of 16 rows).
    const int rowA = (wm * 128 + (l & 15)) * 128;
    const int rowB = (wn * 64  + (l & 15)) * 128;
    const int sl0 = (((l >> 4) | 0) ^ (l & 7)) * 16;   // KS=0: k 0..63
    const int sl1 = (((l >> 4) | 4) ^ (l & 7)) * 16;   // KS=1: k 64..127

    const char* aX0 = lds +         rowA + sl0;
    const char* aX1 = lds +         rowA + sl1;
    const char* bX0 = lds + 32768 + rowB + sl0;
    const char* bX1 = lds + 32768 + rowB + sl1;
    const char* aY0 = lds + 65536 + rowA + sl0;
    const char* aY1 = lds + 65536 + rowA + sl1;
    const char* bY0 = lds + 98304 + rowB + sl0;
    const char* bY1 = lds + 98304 + rowB + sl1;

    i32x4 acc[8][4];
#pragma unroll
    for (int i = 0; i < 8; ++i)
#pragma unroll
        for (int j = 0; j < 4; ++j) acc[i][j] = (i32x4){0, 0, 0, 0};

    const int NT = K / BKB;   // 32 K-tiles

    auto stagePair = [&](const u8* src, char* dst, int kt, int c0, int c1) {
        const u8* s0 = src + (size_t)c0 * 64 * Kz + (size_t)kt * BKB;
        const u8* s1 = src + (size_t)c1 * 64 * Kz + (size_t)kt * BKB;
        __builtin_amdgcn_global_load_lds((const AS1 void*)s0, (AS3 void*)(dst + c0 * 8192), 16, 0, 0);
        __builtin_amdgcn_global_load_lds((const AS1 void*)s1, (AS3 void*)(dst + c1 * 8192), 16, 0, 0);
    };

    // ---- prologue: tile0 full -> buf0; tile1 B -> buf1; counted gate
    stagePair(aSrc, dA0, 0, 0, 2);
    stagePair(bSrc, dB0, 0, 0, 1);
    stagePair(bSrc, dB0, 0, 2, 3);
    stagePair(aSrc, dA0, 0, 1, 3);
    stagePair(bSrc, dB1, 1, 0, 1);
    stagePair(bSrc, dB1, 1, 2, 3);
    asm volatile("s_waitcnt vmcnt(4)" ::: "memory");
    __builtin_amdgcn_s_barrier();

    i32x4 bfr[2][4];

    // ---- main loop: 2 K-tiles per iteration, 8 single-barrier phases.
    // Stage schedule (vmcnt(4)@P4,P8 provably covers every consumed chunk; ledger
    // identical to the 4x-verified bf16 version):
    //  P1:(2i+1).A02->buf1  P2:(2i+1).A13->buf1  P3:e.A02->buf0  P4:e.B01->buf0 +gate
    //  P5:e.B23->buf0       P6:e.A13->buf0       P7:o.B01->buf1  P8:o.B23->buf1 +gate
#pragma unroll 1
    for (int i = 0; i < NT / 2; ++i) {
        const int yt = 2 * i + 1;
        const int e  = (2 * i + 2) & (NT - 1);   // wraps harmlessly on last iter
        const int o  = (2 * i + 3) & (NT - 1);
        phase<0, 0, false>(aX0, bX0, bfr, acc, [&] { stagePair(aSrc, dA1, yt, 0, 2); });
        phase<1, 0, false>(aX1, bX1, bfr, acc, [&] { stagePair(aSrc, dA1, yt, 1, 3); });
        phase<0, 4, false>(aX0, bX0, bfr, acc, [&] { stagePair(aSrc, dA0, e, 0, 2); });
        phase<1, 4, true >(aX1, bX1, bfr, acc, [&] { stagePair(bSrc, dB0, e, 0, 1); });
        phase<0, 0, false>(aY0, bY0, bfr, acc, [&] { stagePair(bSrc, dB0, e, 2, 3); });
        phase<1, 0, false>(aY1, bY1, bfr, acc, [&] { stagePair(aSrc, dA0, e, 1, 3); });
        phase<0, 4, false>(aY0, bY0, bfr, acc, [&] { stagePair(bSrc, dB1, o, 0, 1); });
        phase<1, 4, true >(aY1, bY1, bfr, acc, [&] { stagePair(bSrc, dB1, o, 2, 3); });
    }

    // ---- epilogue (swapped D, R6-verified): col(l&15)->m, row((l>>4)*4+r)->n
    const int mB = tm * BM + wm * 128 + (l & 15);
    const int nB = tn * BN + wn * 64 + 4 * (l >> 4);
    float sxv[8];
#pragma unroll
    for (int f = 0; f < 8; ++f) sxv[f] = sx[mB + f * 16];
#pragma unroll
    for (int fn = 0; fn < 4; ++fn) {
        const int n0 = nB + fn * 16;
        const float4 s4 = *(const float4*)(scale + n0);
        const float4 b4 = *(const float4*)(bias + n0);
#pragma unroll
        for (int f = 0; f < 8; ++f) {
            const int m = mB + f * 16;
            const float sm = sxv[f];
            float4 v;
            v.x = (float)acc[f][fn][0] * (sm * s4.x) + b4.x;
            v.y = (float)acc[f][fn][1] * (sm * s4.y) + b4.y;
            v.z = (float)acc[f][fn][2] * (sm * s4.z) + b4.z;
            v.w = (float)acc[f][fn][3] * (sm * s4.w) + b4.w;
            *(float4*)(C + (size_t)m * N + n0) = v;
        }
    }
}

extern "C" void kernel_launch(void* const* d_in, const int* in_sizes, int n_in,
                              void* d_out, int out_size, void* d_ws, size_t ws_size,
                              hipStream_t stream) {
    const float* x     = (const float*)d_in[0];
    const int*   qw    = (const int*)d_in[1];
    const float* scale = (const float*)d_in[2];
    const float* bias  = (const float*)d_in[3];
    float*       out   = (float*)d_out;

    const int N = in_sizes[2];            // DOUT = 4096
    const int K = in_sizes[1] / N;        // DIN  = 4096
    const int M = in_sizes[0] / K;        // B*S  = 8192

    // workspace: xq [M*K] i8, wq [N*K] i8, sx [M] f32  (~50.4 MB)
    u8*    xq = (u8*)d_ws;
    u8*    wq = xq + (size_t)M * K;
    float* sx = (float*)(wq + (size_t)N * K);

    quant_x_kernel<<<M, 256, 0, stream>>>(x, xq, sx, K);
    quant_w_kernel<<<2048, 256, 0, stream>>>((const int4*)qw, (uint4*)wq, (N * K) / 16);

    const int grid = (M / BM) * (N / BN); // 512
    gemm256_i8<<<grid, 512, 0, stream>>>(xq, wq, sx, scale, bias, out, M, N, K);
}

// Round 8
// 177.906 us; speedup vs baseline: 1.7783x; 1.0126x over previous
//
#include <hip/hip_runtime.h>

typedef unsigned short u16;
typedef unsigned int u32;
typedef unsigned char u8;

typedef int i32x4 __attribute__((ext_vector_type(4)));
typedef float f32x4 __attribute__((ext_vector_type(4)));

#define AS1 __attribute__((address_space(1)))
#define AS3 __attribute__((address_space(3)))

// ---- per-row symmetric i8 quantization of x: one block (256 thr) per row ----
// W is int4 codes in [-8,7]: EXACT in i8 (zero error); only x carries quant error.
__global__ __launch_bounds__(256) void quant_x_kernel(
    const float* __restrict__ x, u8* __restrict__ xq, float* __restrict__ sx, int K)
{
    const int r = blockIdx.x;
    const int t = threadIdx.x;
    const float* xr = x + (size_t)r * K;
    float4 v[4];
    float m = 0.f;
#pragma unroll
    for (int i = 0; i < 4; ++i) {
        v[i] = *(const float4*)(xr + t * 16 + i * 4);
        m = fmaxf(m, fmaxf(fmaxf(fabsf(v[i].x), fabsf(v[i].y)),
                           fmaxf(fabsf(v[i].z), fabsf(v[i].w))));
    }
#pragma unroll
    for (int s = 32; s; s >>= 1) m = fmaxf(m, __shfl_xor(m, s));
    __shared__ float wm[4];
    if ((t & 63) == 0) wm[t >> 6] = m;
    __syncthreads();
    m = fmaxf(fmaxf(wm[0], wm[1]), fmaxf(wm[2], wm[3]));
    const float inv = 127.f / fmaxf(m, 1e-20f);
    if (t == 0) sx[r] = m * (1.f / 127.f);
    u32 o[4];
#pragma unroll
    for (int i = 0; i < 4; ++i) {
        int q0 = (int)rintf(v[i].x * inv), q1 = (int)rintf(v[i].y * inv);
        int q2 = (int)rintf(v[i].z * inv), q3 = (int)rintf(v[i].w * inv);
        o[i] = (u32)(q0 & 255) | ((u32)(q1 & 255) << 8) |
               ((u32)(q2 & 255) << 16) | ((u32)(q3 & 255) << 24);
    }
    *(uint4*)(xq + (size_t)r * K + t * 16) = make_uint4(o[0], o[1], o[2], o[3]);
}

__device__ __forceinline__ u32 pk8(int4 a) {
    return (u32)(a.x & 255) | ((u32)(a.y & 255) << 8) |
           ((u32)(a.z & 255) << 16) | ((u32)(a.w & 255) << 24);
}

// int32 codes [-8,7] -> i8 (exact)
__global__ void quant_w_kernel(const int4* __restrict__ q, uint4* __restrict__ y, int n16) {
    int stride = gridDim.x * blockDim.x;
    for (int i = blockIdx.x * blockDim.x + threadIdx.x; i < n16; i += stride) {
        int4 a = q[4 * i], b = q[4 * i + 1], c = q[4 * i + 2], d = q[4 * i + 3];
        y[i] = make_uint4(pk8(a), pk8(b), pk8(c), pk8(d));
    }
}

// ===== 256x256 i8 GEMM with ONE-PHASE-AHEAD register pipeline =====
// out[m][n] = acc[m][n] * sx[m] * scale[n] + bias[n]
// mfma_i32_16x16x64_i8, BKB=128 (8x16B slots/row), 3-bit slot swizzle (verified 0-conflict),
// 8 phases / 2 K-tiles. Phase p: {stage 1 pair; ds-read NEXT phase's frags (no RAW with
// this phase's MFMA); prio1; 16 MFMA on prev-phase regs; prio0; lgkmcnt(0) [cross-wave WAR:
// all reads done before any wave crosses barrier]; [vmcnt(2) gate]; barrier}.
// MFMA schedule: P1:X/KS0/MLO0 P2:X/KS1/MLO0 P3:X/KS0/MLO4 P4:X/KS1/MLO4, P5-P8 same on Y.
// Read-ahead: P8/P1/P4/P5 issue 8 reads (4 afr + 4 bfr), P2/P3/P6/P7 issue 4.
// Stage schedule + ledger (stage >= last-old-read+1 phase; gate-complete before 1st read):
//  P1:Y.A13  P2:Y.B23  P3:X'.A02 +GATE  P4:X'.B01  P5:X'.A13  P6:X'.B23  P7:Y'.A02 +GATE  P8:Y'.B01
//  (Y of iter i staged P7/P8 prev iter + P1/P2; drained by vmcnt(2)@P3, first read P4. X'
//  staged P3-P6; drained by vmcnt(2)@P7, first read P8. Gates keep 1 pair in flight.)

#define BM 256
#define BN 256
#define BKB 128   // K-bytes per tile (=128 i8)

template<int KSC, int MLOC, bool RDB, int BS, bool GATE, typename F>
__device__ __forceinline__ void phaseRA(
    const char* aN, const char* bN, int mloN,
    i32x4 (&afrC)[4], i32x4 (&afrN)[4],
    i32x4 (&bfr)[2][4], i32x4 (&acc)[8][4], F&& stage)
{
    stage();
    if (RDB) {
#pragma unroll
        for (int fn = 0; fn < 4; ++fn)
            bfr[BS][fn] = *(const i32x4*)(bN + fn * 2048);
    }
#pragma unroll
    for (int f = 0; f < 4; ++f)
        afrN[f] = *(const i32x4*)(aN + (mloN + f) * 2048);
    __builtin_amdgcn_s_setprio(1);
#pragma unroll
    for (int f = 0; f < 4; ++f)
#pragma unroll
        for (int fn = 0; fn < 4; ++fn)
            acc[MLOC + f][fn] = __builtin_amdgcn_mfma_i32_16x16x64_i8(
                bfr[KSC][fn], afrC[f], acc[MLOC + f][fn], 0, 0, 0);  // swapped: D col->m
    __builtin_amdgcn_s_setprio(0);
    asm volatile("s_waitcnt lgkmcnt(0)" ::: "memory");
    if (GATE) asm volatile("s_waitcnt vmcnt(2)" ::: "memory");
    __builtin_amdgcn_s_barrier();
}

__global__ __launch_bounds__(512, 2) void gemm256_i8(
    const u8* __restrict__ A,       // [M][K] i8 (x quantized per-row)
    const u8* __restrict__ W,       // [N][K] i8 (exact int4)
    const float* __restrict__ sx,   // [M] x row scales
    const float* __restrict__ scale,
    const float* __restrict__ bias,
    float* __restrict__ C,
    int M, int N, int K)
{
    __shared__ alignas(1024) char lds[131072];  // buf0(X): A@0 B@32768 ; buf1(Y): A@65536 B@98304

    const int nwg = gridDim.x;
    int bid = blockIdx.x;
    if ((nwg & 7) == 0) { int cpx = nwg >> 3; bid = (bid & 7) * cpx + (bid >> 3); }
    const int ntn = N / BN;
    const int tm = bid / ntn, tn = bid % ntn;

    const int t = threadIdx.x;
    const int l = t & 63;
    const int w = t >> 6;
    const int wm = w >> 2, wn = w & 3;       // 2 x 4 wave grid; wave tile 128x64
    const size_t Kz = (size_t)K;             // row stride in BYTES (i8)

    // ---- staging: linear LDS dest; pre-swizzled global source.
    const int sRow = t >> 3;                              // 0..63 within 64-row chunk
    const int sCol = (((t & 7) ^ ((t >> 3) & 7)) * 16);   // logical byte offset in row
    const u8* aSrc = A + (size_t)(tm * BM + sRow) * Kz + sCol;
    const u8* bSrc = W + (size_t)(tn * BN + sRow) * Kz + sCol;
    const int wByte = w * 1024;

    char* dA0 = lds + wByte;
    char* dB0 = lds + 32768 + wByte;
    char* dA1 = lds + 65536 + wByte;
    char* dB1 = lds + 98304 + wByte;

    // ---- reader bases: logical slot = (l>>4) | (KS<<2); physical = logical ^ (l&7).
    const int rowA = (wm * 128 + (l & 15)) * 128;
    const int rowB = (wn * 64  + (l & 15)) * 128;
    const int sl0 = (((l >> 4) | 0) ^ (l & 7)) * 16;   // KS=0: k 0..63
    const int sl1 = (((l >> 4) | 4) ^ (l & 7)) * 16;   // KS=1: k 64..127

    const char* aX0 = lds +         rowA + sl0;
    const char* aX1 = lds +         rowA + sl1;
    const char* bX0 = lds + 32768 + rowB + sl0;
    const char* bX1 = lds + 32768 + rowB + sl1;
    const char* aY0 = lds + 65536 + rowA + sl0;
    const char* aY1 = lds + 65536 + rowA + sl1;
    const char* bY0 = lds + 98304 + rowB + sl0;
    const char* bY1 = lds + 98304 + rowB + sl1;

    i32x4 acc[8][4];
#pragma unroll
    for (int i = 0; i < 8; ++i)
#pragma unroll
        for (int j = 0; j < 4; ++j) acc[i][j] = (i32x4){0, 0, 0, 0};

    const int NT = K / BKB;   // 32 K-tiles

    auto stagePair = [&](const u8* src, char* dst, int kt, int c0, int c1) {
        const u8* s0 = src + (size_t)c0 * 64 * Kz + (size_t)kt * BKB;
        const u8* s1 = src + (size_t)c1 * 64 * Kz + (size_t)kt * BKB;
        __builtin_amdgcn_global_load_lds((const AS1 void*)s0, (AS3 void*)(dst + c0 * 8192), 16, 0, 0);
        __builtin_amdgcn_global_load_lds((const AS1 void*)s1, (AS3 void*)(dst + c1 * 8192), 16, 0, 0);
    };

    // ---- prologue: X(tile0) full -> buf0; Y(tile1) A02+B01 -> buf1; counted gate;
    // then P0 reads (X KS0 MLO0 frags + bfr[0]) for P1's MFMA.
    stagePair(aSrc, dA0, 0, 0, 2);
    stagePair(bSrc, dB0, 0, 0, 1);
    stagePair(bSrc, dB0, 0, 2, 3);
    stagePair(aSrc, dA0, 0, 1, 3);
    stagePair(aSrc, dA1, 1, 0, 2);   // Y.A02
    stagePair(bSrc, dB1, 1, 0, 1);   // Y.B01
    asm volatile("s_waitcnt vmcnt(4)" ::: "memory");
    __builtin_amdgcn_s_barrier();

    i32x4 bfr[2][4];
    i32x4 afrA[4], afrB[4];
#pragma unroll
    for (int fn = 0; fn < 4; ++fn)
        bfr[0][fn] = *(const i32x4*)(bX0 + fn * 2048);
#pragma unroll
    for (int f = 0; f < 4; ++f)
        afrA[f] = *(const i32x4*)(aX0 + f * 2048);

#pragma unroll 1
    for (int i = 0; i < NT / 2; ++i) {
        const int yt = 2 * i + 1;
        const int e  = (2 * i + 2) & (NT - 1);   // wraps harmlessly on last iter
        const int o  = (2 * i + 3) & (NT - 1);
        // P1: MFMA X/KS0/MLO0(afrA); read aX1 MLO0 -> afrB, bX1 -> bfr[1]; stage Y.A13
        phaseRA<0, 0, true , 1, false>(aX1, bX1, 0, afrA, afrB, bfr, acc,
            [&] { stagePair(aSrc, dA1, yt, 1, 3); });
        // P2: MFMA X/KS1/MLO0(afrB); read aX0 MLO4 -> afrA; stage Y.B23
        phaseRA<1, 0, false, 0, false>(aX0, bX0, 4, afrB, afrA, bfr, acc,
            [&] { stagePair(bSrc, dB1, yt, 2, 3); });
        // P3: MFMA X/KS0/MLO4(afrA); read aX1 MLO4 -> afrB; stage X'.A02; GATE
        phaseRA<0, 4, false, 0, true >(aX1, bX1, 4, afrA, afrB, bfr, acc,
            [&] { stagePair(aSrc, dA0, e, 0, 2); });
        // P4: MFMA X/KS1/MLO4(afrB); read aY0 MLO0 -> afrA, bY0 -> bfr[0]; stage X'.B01
        phaseRA<1, 4, true , 0, false>(aY0, bY0, 0, afrB, afrA, bfr, acc,
            [&] { stagePair(bSrc, dB0, e, 0, 1); });
        // P5: MFMA Y/KS0/MLO0(afrA); read aY1 MLO0 -> afrB, bY1 -> bfr[1]; stage X'.A13
        phaseRA<0, 0, true , 1, false>(aY1, bY1, 0, afrA, afrB, bfr, acc,
            [&] { stagePair(aSrc, dA0, e, 1, 3); });
        // P6: MFMA Y/KS1/MLO0(afrB); read aY0 MLO4 -> afrA; stage X'.B23
        phaseRA<1, 0, false, 0, false>(aY0, bY0, 4, afrB, afrA, bfr, acc,
            [&] { stagePair(bSrc, dB0, e, 2, 3); });
        // P7: MFMA Y/KS0/MLO4(afrA); read aY1 MLO4 -> afrB; stage Y'.A02; GATE
        phaseRA<0, 4, false, 0, true >(aY1, bY1, 4, afrA, afrB, bfr, acc,
            [&] { stagePair(aSrc, dA1, o, 0, 2); });
        // P8: MFMA Y/KS1/MLO4(afrB); read aX0 MLO0 -> afrA, bX0 -> bfr[0]; stage Y'.B01
        phaseRA<1, 4, true , 0, false>(aX0, bX0, 0, afrB, afrA, bfr, acc,
            [&] { stagePair(bSrc, dB1, o, 0, 1); });
    }

    // ---- epilogue (swapped D): col(l&15)->m, row((l>>4)*4+r)->n
    const int mB = tm * BM + wm * 128 + (l & 15);
    const int nB = tn * BN + wn * 64 + 4 * (l >> 4);
    float sxv[8];
#pragma unroll
    for (int f = 0; f < 8; ++f) sxv[f] = sx[mB + f * 16];
#pragma unroll
    for (int fn = 0; fn < 4; ++fn) {
        const int n0 = nB + fn * 16;
        const float4 s4 = *(const float4*)(scale + n0);
        const float4 b4 = *(const float4*)(bias + n0);
#pragma unroll
        for (int f = 0; f < 8; ++f) {
            const int m = mB + f * 16;
            const float sm = sxv[f];
            float4 v;
            v.x = (float)acc[f][fn][0] * (sm * s4.x) + b4.x;
            v.y = (float)acc[f][fn][1] * (sm * s4.y) + b4.y;
            v.z = (float)acc[f][fn][2] * (sm * s4.z) + b4.z;
            v.w = (float)acc[f][fn][3] * (sm * s4.w) + b4.w;
            *(float4*)(C + (size_t)m * N + n0) = v;
        }
    }
}

extern "C" void kernel_launch(void* const* d_in, const int* in_sizes, int n_in,
                              void* d_out, int out_size, void* d_ws, size_t ws_size,
                              hipStream_t stream) {
    const float* x     = (const float*)d_in[0];
    const int*   qw    = (const int*)d_in[1];
    const float* scale = (const float*)d_in[2];
    const float* bias  = (const float*)d_in[3];
    float*       out   = (float*)d_out;

    const int N = in_sizes[2];            // DOUT = 4096
    const int K = in_sizes[1] / N;        // DIN  = 4096
    const int M = in_sizes[0] / K;        // B*S  = 8192

    // workspace: xq [M*K] i8, wq [N*K] i8, sx [M] f32  (~50.4 MB)
    u8*    xq = (u8*)d_ws;
    u8*    wq = xq + (size_t)M * K;
    float* sx = (float*)(wq + (size_t)N * K);

    quant_x_kernel<<<M, 256, 0, stream>>>(x, xq, sx, K);
    quant_w_kernel<<<2048, 256, 0, stream>>>((const int4*)qw, (uint4*)wq, (N * K) / 16);

    const int grid = (M / BM) * (N / BN); // 512
    gemm256_i8<<<grid, 512, 0, stream>>>(xq, wq, sx, scale, bias, out, M, N, K);
}